// Round 4
// baseline (117.004 us; speedup 1.0000x reference)
//
#include <hip/hip_runtime.h>
#include <stdint.h>

// Radius-graph edge list, B=4, N=2048, cutoff 5.0.
// Output [2, B*P] int32: compacted valid edges (ascending flat index), -1 pad.
// Pipeline (2 kernels):
//   pass1   : fill own out-slice with -1; incremental (b,i,j) row-walk with
//             cached pi; hot loop accumulates only an 8-bit hit mask/thread;
//             rare epilogue (skipped per-wave when no hits) does ballots,
//             32-slot scan, count, and stash of (gi,gj). Stash stride = 2048
//             = chunk size, so overflow is impossible.
//   finalize: single block. uint4-scan of 4094 block counts; each thread then
//             copies its 16 blocks' stashed edges to final global offsets.

namespace {
constexpr int kB = 4;
constexpr int kN = 2048;
constexpr int kP = kN * (kN - 1) / 2;              // 2096128
constexpr long long kTotal = (long long)kB * kP;   // 8384512
constexpr int kBlock = 256;
constexpr int kItems = 8;
constexpr int kChunk = kBlock * kItems;            // 2048
constexpr int kNBlk = (int)(kTotal / kChunk);      // 4094 (exact, no tail)
constexpr float kCut2 = 25.0f;                     // 5.0^2
constexpr int kStride = kChunk;                    // stash slots per block (max possible)
}  // namespace

// p in [0,P) -> (i,j), i<j, triu row-major. Closed-form sqrt guess + exact
// integer fixup. C(i) = i*(4095-i)/2. disc < 2^24 so float sqrt is tight.
__device__ __forceinline__ void decode_pair(int p, int& i, int& j) {
  float t = sqrtf((float)(16769025 - 8 * p));
  int ii = (int)((4095.0f - t) * 0.5f);
  ii = ii < 0 ? 0 : (ii > kN - 2 ? kN - 2 : ii);
  while (ii > 0 && (ii * (4095 - ii)) / 2 > p) --ii;
  while (ii < kN - 2 && ((ii + 1) * (4094 - ii)) / 2 <= p) ++ii;
  i = ii;
  j = ii + 1 + (p - (ii * (4095 - ii)) / 2);
}

__global__ __launch_bounds__(kBlock) void pass1_kernel(const float* __restrict__ x,
                                                       uint32_t* __restrict__ counts,
                                                       int2* __restrict__ stash,
                                                       int* __restrict__ out) {
  const int t = threadIdx.x;
  const int wave = t >> 6, lane = t & 63;
  const int bid = blockIdx.x;
  const int base = bid * kChunk;

  // Fill this block's slice of both output rows with -1 (2048 ints each).
  {
    const int4 m1 = make_int4(-1, -1, -1, -1);
    int4* o0 = (int4*)out + (base >> 2);
    int4* o1 = (int4*)(out + kTotal) + (base >> 2);
    o0[t] = m1;
    o0[t + kBlock] = m1;
    o1[t] = m1;
    o1[t + kBlock] = m1;
  }
  if (bid == 0 && t < 2) counts[kNBlk + t] = 0;  // pad so finalize can uint4-load

  // One sqrt-decode per thread per block, then incremental row-walk (+256/item).
  int b = base / kP;
  int p = base - b * kP + t;
  if (p >= kP) { p -= kP; ++b; }
  int i, j;
  decode_pair(p, i, j);
  int eb = b * (kN * 3);  // element base of batch b

  float pix = x[eb + 3 * i], piy = x[eb + 3 * i + 1], piz = x[eb + 3 * i + 2];

  uint32_t hits = 0;  // bit k = item k is an edge
#pragma unroll
  for (int k = 0; k < kItems; ++k) {
    int ej = eb + 3 * j;
    float dx = pix - x[ej], dy = piy - x[ej + 1], dz = piz - x[ej + 2];
    if (dx * dx + dy * dy + dz * dz <= kCut2) hits |= (1u << k);
    if (k < kItems - 1) {
      j += kBlock;
      if (j >= kN) {  // ~20% of items, mostly wave-coherent
        do {
          int ex = j - kN;
          ++i;
          if (i >= kN - 1) { i = 0; eb += kN * 3; }
          j = i + 1 + ex;
        } while (j >= kN);
        int ei = eb + 3 * i;
        pix = x[ei]; piy = x[ei + 1]; piz = x[ei + 2];
      }
    }
  }

  __shared__ uint32_t slot[32];
  if (t < 32) slot[t] = 0;
  __syncthreads();

  const bool waveany = (__ballot(hits != 0) != 0ULL);  // wave-uniform
  if (waveany) {
#pragma unroll
    for (int k = 0; k < kItems; ++k) {
      unsigned long long m = __ballot((hits >> k) & 1u);
      if (m != 0ULL && lane == 0) slot[k * 4 + wave] = (uint32_t)__popcll(m);
    }
  }
  __syncthreads();
  if (t < 32) {  // exclusive scan of 32 (item,wave) counts; write block total
    uint32_t v = slot[t];
    uint32_t run = v;
    for (int off = 1; off < 32; off <<= 1) {
      uint32_t u = __shfl_up(run, off, 64);
      if (t >= off) run += u;
    }
    slot[t] = run - v;
    if (t == 31) counts[bid] = run;
  }
  __syncthreads();
  if (waveany) {
#pragma unroll
    for (int k = 0; k < kItems; ++k) {
      bool f = (hits >> k) & 1u;
      unsigned long long m = __ballot(f);
      if (m != 0ULL && f) {  // rare: ~3 hits per block total
        int pf = base + k * kBlock + t;
        int hb = pf / kP;
        int hp = pf - hb * kP;
        int hi, hj;
        decode_pair(hp, hi, hj);
        uint32_t pos = slot[k * 4 + wave] +
                       (uint32_t)__popcll(m & ((1ULL << lane) - 1ULL));
        stash[(size_t)bid * kStride + pos] = make_int2(hb * kN + hi, hb * kN + hj);
      }
    }
  }
}

__global__ __launch_bounds__(kBlock) void finalize_kernel(const uint32_t* __restrict__ counts,
                                                          const int2* __restrict__ stash,
                                                          int* __restrict__ out) {
  __shared__ uint32_t s[kBlock];
  const int t = threadIdx.x;
  const uint4* c4 = (const uint4*)counts;  // [4096] incl. zero pad
  uint32_t c[16], loc[16];
  uint32_t sum = 0;
#pragma unroll
  for (int q = 0; q < 4; ++q) {
    uint4 v = c4[t * 4 + q];
    c[q * 4 + 0] = v.x; c[q * 4 + 1] = v.y; c[q * 4 + 2] = v.z; c[q * 4 + 3] = v.w;
  }
#pragma unroll
  for (int q = 0; q < 16; ++q) { loc[q] = sum; sum += c[q]; }
  s[t] = sum;
  __syncthreads();
  for (int off = 1; off < kBlock; off <<= 1) {  // Hillis-Steele inclusive
    uint32_t u = (t >= off) ? s[t - off] : 0u;
    __syncthreads();
    if (t >= off) s[t] += u;
    __syncthreads();
  }
  const uint32_t tbase = (t == 0) ? 0u : s[t - 1];
  // Copy this thread's 16 blocks' edges to their final positions.
#pragma unroll
  for (int q = 0; q < 16; ++q) {
    int idx = t * 16 + q;
    uint32_t cnt = c[q];            // 0 for padded idx >= kNBlk
    if (cnt != 0) {
      uint32_t off = tbase + loc[q];
      const int2* sp = stash + (size_t)idx * kStride;
      for (uint32_t e = 0; e < cnt; ++e) {
        int2 v = sp[e];
        out[off + e] = v.x;
        out[(size_t)kTotal + off + e] = v.y;
      }
    }
  }
}

extern "C" void kernel_launch(void* const* d_in, const int* in_sizes, int n_in,
                              void* d_out, int out_size, void* d_ws, size_t ws_size,
                              hipStream_t stream) {
  const float* x = (const float*)d_in[0];
  int* out = (int*)d_out;
  uint32_t* counts = (uint32_t*)d_ws;                 // [4096] (2 pad)
  int2* stash = (int2*)(counts + 4096);               // [4094 * 2048] ~67 MB

  hipLaunchKernelGGL(pass1_kernel, dim3(kNBlk), dim3(kBlock), 0, stream, x, counts,
                     stash, out);
  hipLaunchKernelGGL(finalize_kernel, dim3(1), dim3(kBlock), 0, stream, counts, stash,
                     out);
}

// Round 5
// 93.482 us; speedup vs baseline: 1.2516x; 1.2516x over previous
//
#include <hip/hip_runtime.h>
#include <stdint.h>

// Radius-graph edge list, B=4, N=2048, cutoff 5.0.
// Output [2, B*P] int32: compacted valid edges (ascending flat index), -1 pad.
// Pipeline (3 kernels — the round-3 proven structure):
//   pass1  : fill own out-slice with -1; incremental (b,i,j) row-walk with
//            cached pi; hot loop accumulates only an 8-bit hit mask/thread;
//            epilogue does ballots + 32-slot scan + count + stash (kCap=128,
//            compact 4.2 MB -> L2/L3-warm for scatter).
//   scan   : single-block exclusive scan of 4094 block counts (uint4 loads).
//   scatter: 4094 blocks copy stash to final offsets (parallel, latency-
//            tolerant); exact recompute fallback if a block's count > kCap.

namespace {
constexpr int kB = 4;
constexpr int kN = 2048;
constexpr int kP = kN * (kN - 1) / 2;              // 2096128
constexpr long long kTotal = (long long)kB * kP;   // 8384512
constexpr int kBlock = 256;
constexpr int kItems = 8;
constexpr int kChunk = kBlock * kItems;            // 2048
constexpr int kNBlk = (int)(kTotal / kChunk);      // 4094 (exact, no tail)
constexpr float kCut2 = 25.0f;                     // 5.0^2
constexpr int kScanPer = 16;                       // 256*16 = 4096 >= 4094
constexpr int kCap = 128;                          // stash slots per block
}  // namespace

// p in [0,P) -> (i,j), i<j, triu row-major. Closed-form sqrt guess + exact
// integer fixup. C(i) = i*(4095-i)/2. disc < 2^24 so float sqrt is tight.
__device__ __forceinline__ void decode_pair(int p, int& i, int& j) {
  float t = sqrtf((float)(16769025 - 8 * p));
  int ii = (int)((4095.0f - t) * 0.5f);
  ii = ii < 0 ? 0 : (ii > kN - 2 ? kN - 2 : ii);
  while (ii > 0 && (ii * (4095 - ii)) / 2 > p) --ii;
  while (ii < kN - 2 && ((ii + 1) * (4094 - ii)) / 2 <= p) ++ii;
  i = ii;
  j = ii + 1 + (p - (ii * (4095 - ii)) / 2);
}

__device__ __forceinline__ bool pair_test(const float* __restrict__ x, int b, int p,
                                          int& gi, int& gj) {
  int i, j;
  decode_pair(p, i, j);
  const float* xb = x + (size_t)b * kN * 3;
  float dx = xb[3 * i + 0] - xb[3 * j + 0];
  float dy = xb[3 * i + 1] - xb[3 * j + 1];
  float dz = xb[3 * i + 2] - xb[3 * j + 2];
  gi = b * kN + i;
  gj = b * kN + j;
  return dx * dx + dy * dy + dz * dz <= kCut2;
}

__global__ __launch_bounds__(kBlock) void pass1_kernel(const float* __restrict__ x,
                                                       uint32_t* __restrict__ counts,
                                                       int2* __restrict__ stash,
                                                       int* __restrict__ out) {
  const int t = threadIdx.x;
  const int wave = t >> 6, lane = t & 63;
  const int bid = blockIdx.x;
  const int base = bid * kChunk;

  // Fill this block's slice of both output rows with -1 (2048 ints each).
  {
    const int4 m1 = make_int4(-1, -1, -1, -1);
    int4* o0 = (int4*)out + (base >> 2);
    int4* o1 = (int4*)(out + kTotal) + (base >> 2);
    o0[t] = m1;
    o0[t + kBlock] = m1;
    o1[t] = m1;
    o1[t + kBlock] = m1;
  }
  if (bid == 0 && t < 2) counts[kNBlk + t] = 0;  // pad so scan can uint4-load

  // One sqrt-decode per thread per block, then incremental row-walk (+256/item).
  int b = base / kP;
  int p = base - b * kP + t;
  if (p >= kP) { p -= kP; ++b; }
  int i, j;
  decode_pair(p, i, j);
  int ib = b * kN;  // point-index base of batch b

  const float3* __restrict__ x3 = (const float3*)x;
  float3 pi = x3[ib + i];

  uint32_t hits = 0;  // bit k = item k is an edge
#pragma unroll
  for (int k = 0; k < kItems; ++k) {
    float3 pj = x3[ib + j];
    float dx = pi.x - pj.x, dy = pi.y - pj.y, dz = pi.z - pj.z;
    if (dx * dx + dy * dy + dz * dz <= kCut2) hits |= (1u << k);
    if (k < kItems - 1) {
      j += kBlock;
      if (j >= kN) {  // ~20% of items, mostly wave-coherent
        do {
          int ex = j - kN;
          ++i;
          if (i >= kN - 1) { i = 0; ib += kN; }
          j = i + 1 + ex;
        } while (j >= kN);
        pi = x3[ib + i];
      }
    }
  }

  __shared__ uint32_t slot[32];
  if (t < 32) slot[t] = 0;
  __syncthreads();

  const bool waveany = (__ballot(hits != 0) != 0ULL);  // wave-uniform
  if (waveany) {
#pragma unroll
    for (int k = 0; k < kItems; ++k) {
      unsigned long long m = __ballot((hits >> k) & 1u);
      if (m != 0ULL && lane == 0) slot[k * 4 + wave] = (uint32_t)__popcll(m);
    }
  }
  __syncthreads();
  if (t < 32) {  // exclusive scan of 32 (item,wave) counts; write block total
    uint32_t v = slot[t];
    uint32_t run = v;
    for (int off = 1; off < 32; off <<= 1) {
      uint32_t u = __shfl_up(run, off, 64);
      if (t >= off) run += u;
    }
    slot[t] = run - v;
    if (t == 31) counts[bid] = run;
  }
  __syncthreads();
  if (waveany) {
#pragma unroll
    for (int k = 0; k < kItems; ++k) {
      bool f = (hits >> k) & 1u;
      unsigned long long m = __ballot(f);
      if (m != 0ULL && f) {  // rare: ~3 hits per block total
        int pf = base + k * kBlock + t;
        int hb = pf / kP;
        int hp = pf - hb * kP;
        int hi, hj;
        decode_pair(hp, hi, hj);
        uint32_t pos = slot[k * 4 + wave] +
                       (uint32_t)__popcll(m & ((1ULL << lane) - 1ULL));
        if (pos < (uint32_t)kCap)
          stash[(size_t)bid * kCap + pos] = make_int2(hb * kN + hi, hb * kN + hj);
      }
    }
  }
}

__global__ __launch_bounds__(kBlock) void scan_kernel(const uint32_t* __restrict__ counts,
                                                      uint32_t* __restrict__ offsets) {
  __shared__ uint32_t s[kBlock];
  const int t = threadIdx.x;
  const uint4* c4 = (const uint4*)counts;  // [4096] incl. zero pad
  uint32_t loc[kScanPer];
  uint32_t sum = 0;
#pragma unroll
  for (int q = 0; q < 4; ++q) {
    uint4 c = c4[t * 4 + q];
    loc[q * 4 + 0] = sum; sum += c.x;
    loc[q * 4 + 1] = sum; sum += c.y;
    loc[q * 4 + 2] = sum; sum += c.z;
    loc[q * 4 + 3] = sum; sum += c.w;
  }
  s[t] = sum;
  __syncthreads();
  for (int off = 1; off < kBlock; off <<= 1) {
    uint32_t u = (t >= off) ? s[t - off] : 0u;
    __syncthreads();
    if (t >= off) s[t] += u;
    __syncthreads();
  }
  uint32_t base = (t == 0) ? 0u : s[t - 1];
#pragma unroll
  for (int k = 0; k < kScanPer; ++k) {
    int idx = t * kScanPer + k;
    if (idx < kNBlk) offsets[idx] = base + loc[k];
  }
}

__global__ __launch_bounds__(kBlock) void scatter_kernel(const float* __restrict__ x,
                                                         const uint32_t* __restrict__ counts,
                                                         const uint32_t* __restrict__ offsets,
                                                         const int2* __restrict__ stash,
                                                         int* __restrict__ out) {
  const int bid = blockIdx.x;
  const int t = threadIdx.x;
  const uint32_t cnt = counts[bid];
  if (cnt == 0) return;
  const uint32_t off = offsets[bid];
  if (cnt <= (uint32_t)kCap) {
    for (uint32_t e = t; e < cnt; e += kBlock) {
      int2 v = stash[(size_t)bid * kCap + e];
      out[off + e] = v.x;
      out[(size_t)kTotal + off + e] = v.y;
    }
    return;
  }
  // Overflow fallback (count > kCap): recompute this block's edges with
  // ballot ranks and write directly. Deterministic + exact.
  const int wave = t >> 6, lane = t & 63;
  const int base = bid * kChunk;
  const int bb0 = base / kP;
  const int p0 = base - bb0 * kP;
  __shared__ uint32_t slot[kItems * 4];
  unsigned long long masks[kItems];
  int gi[kItems], gj[kItems];
  bool fl[kItems];
  for (int k = 0; k < kItems; ++k) {
    int o = k * kBlock + t;
    int b = bb0, p = p0 + o;
    if (p >= kP) { p -= kP; ++b; }
    fl[k] = pair_test(x, b, p, gi[k], gj[k]);
    masks[k] = __ballot(fl[k]);
    if (lane == 0) slot[k * 4 + wave] = (uint32_t)__popcll(masks[k]);
  }
  __syncthreads();
  if (t == 0) {
    uint32_t run = 0;
    for (int s = 0; s < kItems * 4; ++s) {
      uint32_t c = slot[s];
      slot[s] = run;
      run += c;
    }
  }
  __syncthreads();
  for (int k = 0; k < kItems; ++k) {
    if (fl[k]) {
      uint32_t pos = off + slot[k * 4 + wave] +
                     (uint32_t)__popcll(masks[k] & ((1ULL << lane) - 1ULL));
      out[pos] = gi[k];
      out[(size_t)kTotal + pos] = gj[k];
    }
  }
}

extern "C" void kernel_launch(void* const* d_in, const int* in_sizes, int n_in,
                              void* d_out, int out_size, void* d_ws, size_t ws_size,
                              hipStream_t stream) {
  const float* x = (const float*)d_in[0];
  int* out = (int*)d_out;
  uint32_t* counts = (uint32_t*)d_ws;                 // [4096] (2 pad)
  uint32_t* offsets = counts + 4096;                  // [4094]
  int2* stash = (int2*)(offsets + 4096);              // [4094 * kCap] ~4.2 MB

  hipLaunchKernelGGL(pass1_kernel, dim3(kNBlk), dim3(kBlock), 0, stream, x, counts,
                     stash, out);
  hipLaunchKernelGGL(scan_kernel, dim3(1), dim3(kBlock), 0, stream, counts, offsets);
  hipLaunchKernelGGL(scatter_kernel, dim3(kNBlk), dim3(kBlock), 0, stream, x, counts,
                     offsets, stash, out);
}